// Round 2
// baseline (5574.390 us; speedup 1.0000x reference)
//
#include <hip/hip_runtime.h>
#include <hip/hip_bf16.h>
#include <math.h>

#define N_INPUTS 65536
#define NUM_EMB 4096
#define DIM 256
#define BM 64
#define TN 16
#define XS_STRIDE 260  // dwords, padded (multiple of 4 for b128 alignment)

// ---- numpy pairwise sum of squares, bit-exact replication ----
// numpy FLOAT_pairwise_sum: n=256 -> pw(128)+pw(128); each 128-block uses
// 8 accumulators unrolled by 8, combined ((r0+r1)+(r2+r3))+((r4+r5)+(r6+r7)).
// __fmul_rn/__fadd_rn prevent FMA contraction (numpy squares, THEN sums).
__device__ __forceinline__ float pw128_sq(const float* __restrict__ a) {
    float r[8];
    #pragma unroll
    for (int j = 0; j < 8; ++j) r[j] = __fmul_rn(a[j], a[j]);
    #pragma unroll
    for (int i = 8; i < 128; i += 8)
        #pragma unroll
        for (int j = 0; j < 8; ++j)
            r[j] = __fadd_rn(r[j], __fmul_rn(a[i + j], a[i + j]));
    return __fadd_rn(__fadd_rn(__fadd_rn(r[0], r[1]), __fadd_rn(r[2], r[3])),
                     __fadd_rn(__fadd_rn(r[4], r[5]), __fadd_rn(r[6], r[7])));
}
__device__ __forceinline__ float pw256_sq(const float* __restrict__ a) {
    return __fadd_rn(pw128_sq(a), pw128_sq(a + 128));
}

// ---------- kernel 0a: codebook row norms (numpy pairwise order) ----------
__global__ void ne2_kernel(const float* __restrict__ cb, float* __restrict__ ne2) {
    int k = blockIdx.x * blockDim.x + threadIdx.x;
    if (k < NUM_EMB) ne2[k] = pw256_sq(cb + (size_t)k * DIM);
}

// ---------- kernel 0b: input row norms (numpy pairwise order) ----------
__global__ void nx2_kernel(const float* __restrict__ x, float* __restrict__ nx2) {
    int i = blockIdx.x * blockDim.x + threadIdx.x;
    if (i < N_INPUTS) nx2[i] = pw256_sq(x + (size_t)i * DIM);
}

// ---------- kernel 1: argmin + quantize + partial loss + counts ----------
__global__ __launch_bounds__(256) void vq_main(
        const float* __restrict__ x, const float* __restrict__ cb,
        const float* __restrict__ ne2, const float* __restrict__ nx2,
        float* __restrict__ out_q, float* __restrict__ out_idx,
        int* __restrict__ counts, float* __restrict__ partials) {
    __shared__ float xs[BM * XS_STRIDE];
    __shared__ float mval[4][64];
    __shared__ int   midx[4][64];
    __shared__ int   sidx[64];
    __shared__ float red[256];

    const int t = threadIdx.x;
    const int b = blockIdx.x;
    const size_t rowbase = (size_t)b * BM;

    // ---- stage x tile (64 rows x 256 f32) into padded LDS, coalesced ----
    {
        const float4* g = (const float4*)(x + rowbase * DIM);
        float4* s4 = (float4*)xs;
        #pragma unroll
        for (int k = 0; k < 16; ++k) {
            int p = t + k * 256;          // float4 index 0..4095
            int r = p >> 6, c = p & 63;
            s4[r * (XS_STRIDE / 4) + c] = g[p];
        }
    }
    __syncthreads();

    const int w = t >> 6, lane = t & 63;
    // force scalar (wave-uniform) code base so codebook loads become s_load
    const int nbase0 = __builtin_amdgcn_readfirstlane(w * 1024);

    const float nx2r = nx2[rowbase + lane];
    float minv = INFINITY;
    int   mini = 0;
    const float* xrow = xs + lane * XS_STRIDE;

    for (int nt = 0; nt < 1024; nt += TN) {
        const int nb = nbase0 + nt;
        float acc[TN];
        #pragma unroll
        for (int j = 0; j < TN; ++j) acc[j] = 0.f;

        for (int d = 0; d < DIM; d += 16) {
            float4 xa = *(const float4*)(xrow + d);
            float4 xb = *(const float4*)(xrow + d + 4);
            float4 xc = *(const float4*)(xrow + d + 8);
            float4 xd = *(const float4*)(xrow + d + 12);
            #pragma unroll
            for (int j = 0; j < TN; ++j) {
                const float4* cr = (const float4*)(cb + (size_t)(nb + j) * DIM + d);
                float4 e0 = cr[0], e1 = cr[1], e2 = cr[2], e3 = cr[3];
                float a = acc[j];
                a = fmaf(xa.x, e0.x, a); a = fmaf(xa.y, e0.y, a);
                a = fmaf(xa.z, e0.z, a); a = fmaf(xa.w, e0.w, a);
                a = fmaf(xb.x, e1.x, a); a = fmaf(xb.y, e1.y, a);
                a = fmaf(xb.z, e1.z, a); a = fmaf(xb.w, e1.w, a);
                a = fmaf(xc.x, e2.x, a); a = fmaf(xc.y, e2.y, a);
                a = fmaf(xc.z, e2.z, a); a = fmaf(xc.w, e2.w, a);
                a = fmaf(xd.x, e3.x, a); a = fmaf(xd.y, e3.y, a);
                a = fmaf(xd.z, e3.z, a); a = fmaf(xd.w, e3.w, a);
                acc[j] = a;
            }
        }
        #pragma unroll
        for (int j = 0; j < TN; ++j) {
            // replicate np f32 rounding: t1 = (|x|^2 + |e|^2); d = t1 - 2*dot
            float t1 = __fadd_rn(nx2r, ne2[nb + j]);
            float s  = __fsub_rn(t1, __fmul_rn(2.f, acc[j]));
            if (s < minv) { minv = s; mini = nb + j; }  // strict < : lowest idx wins
        }
    }
    mval[w][lane] = minv;
    midx[w][lane] = mini;
    __syncthreads();

    if (t < 64) {
        float bv = mval[0][t];
        int   bi = midx[0][t];
        #pragma unroll
        for (int ww = 1; ww < 4; ++ww) {
            float v = mval[ww][t];
            if (v < bv) { bv = v; bi = midx[ww][t]; }  // waves in ascending code order
        }
        sidx[t] = bi;
        out_idx[rowbase + t] = (float)bi;
        atomicAdd(&counts[bi], 1);
    }
    __syncthreads();

    // ---- quantized write + squared-error partial ----
    const int r  = t >> 2;            // row within tile
    const int c0 = (t & 3) * 16;      // float4 column start
    const int qi = sidx[r];
    const float4* cr  = (const float4*)(cb + (size_t)qi * DIM);
    float4*       oq  = (float4*)(out_q + (rowbase + r) * DIM);
    const float4* xr4 = (const float4*)(xs + r * XS_STRIDE);
    float ss = 0.f;
    #pragma unroll
    for (int k = 0; k < 16; ++k) {
        float4 q  = cr[c0 + k];
        float4 xv = xr4[c0 + k];
        oq[c0 + k] = q;
        float dx = xv.x - q.x, dy = xv.y - q.y, dz = xv.z - q.z, dw = xv.w - q.w;
        ss += dx * dx + dy * dy + dz * dz + dw * dw;
    }
    red[t] = ss;
    __syncthreads();
    for (int st = 128; st; st >>= 1) {
        if (t < st) red[t] += red[t + st];
        __syncthreads();
    }
    if (t == 0) partials[b] = red[0];
}

// ---------- kernel 2: finalize loss + perplexity ----------
__global__ void finalize_kernel(const float* __restrict__ partials, int np,
                                const int* __restrict__ counts,
                                float* __restrict__ out_loss,
                                float* __restrict__ out_perp) {
    __shared__ double sh[256];
    const int t = threadIdx.x;
    double s = 0.0;
    for (int i = t; i < np; i += 256) s += (double)partials[i];
    sh[t] = s; __syncthreads();
    for (int st = 128; st; st >>= 1) { if (t < st) sh[t] += sh[t + st]; __syncthreads(); }
    double sse = sh[0];
    __syncthreads();
    double h = 0.0;
    for (int k = t; k < NUM_EMB; k += 256) {
        double p = (double)counts[k] / (double)N_INPUTS;
        h -= p * log(p + 1e-10);
    }
    sh[t] = h; __syncthreads();
    for (int st = 128; st; st >>= 1) { if (t < st) sh[t] += sh[t + st]; __syncthreads(); }
    if (t == 0) {
        double mse = sse / ((double)N_INPUTS * (double)DIM);
        out_loss[0] = (float)(1.25 * mse);   // q_latent + 0.25*e_latent, both == mse
        out_perp[0] = (float)exp(sh[0]);
    }
}

extern "C" void kernel_launch(void* const* d_in, const int* in_sizes, int n_in,
                              void* d_out, int out_size, void* d_ws, size_t ws_size,
                              hipStream_t stream) {
    const float* x  = (const float*)d_in[0];
    const float* cb = (const float*)d_in[1];
    float* out      = (float*)d_out;

    float* out_q    = out;                              // 65536*256
    float* out_loss = out + (size_t)N_INPUTS * DIM;     // +16777216
    float* out_perp = out_loss + 1;
    float* out_idx  = out_perp + 1;                     // 65536 (written as float)

    float* ne2      = (float*)d_ws;                     // 4096 f32
    int*   counts   = (int*)((char*)d_ws + 16384);      // 4096 i32
    float* partials = (float*)((char*)d_ws + 32768);    // 1024 f32
    float* nx2      = (float*)((char*)d_ws + 36864);    // 65536 f32

    hipMemsetAsync(counts, 0, NUM_EMB * sizeof(int), stream);
    ne2_kernel<<<NUM_EMB / 256, 256, 0, stream>>>(cb, ne2);
    nx2_kernel<<<N_INPUTS / 256, 256, 0, stream>>>(x, nx2);
    vq_main<<<N_INPUTS / BM, 256, 0, stream>>>(x, cb, ne2, nx2, out_q, out_idx,
                                               counts, partials);
    finalize_kernel<<<1, 256, 0, stream>>>(partials, N_INPUTS / BM, counts,
                                           out_loss, out_perp);
}

// Round 4
// 986.427 us; speedup vs baseline: 5.6511x; 5.6511x over previous
//
#include <hip/hip_runtime.h>
#include <hip/hip_bf16.h>
#include <math.h>

#define N_INPUTS 65536
#define NUM_EMB 4096
#define DIM 256
#define TAU 1.8e-3f
#define QSCALE 500000.0f
#define CAP 95

typedef __attribute__((ext_vector_type(8))) short bf16x8;
typedef __attribute__((ext_vector_type(4))) float f32x4;

// ---- monotone float<->uint packing (ascending uint == ascending float) ----
__device__ __forceinline__ unsigned enc32(float f) {
    unsigned u = __float_as_uint(f);
    return (u & 0x80000000u) ? ~u : (u | 0x80000000u);
}
__device__ __forceinline__ float dec32(unsigned e) {
    unsigned u = (e & 0x80000000u) ? (e & 0x7FFFFFFFu) : ~e;
    return __uint_as_float(u);
}
__device__ __forceinline__ unsigned short f2bf_rne(float f) {
    unsigned u = __float_as_uint(f);
    return (unsigned short)((u + 0x7FFFu + ((u >> 16) & 1u)) >> 16);
}

// ---- numpy pairwise sum of squares (bit-exact, proven in round 2) ----
__device__ __forceinline__ float pw128_sq(const float* __restrict__ a) {
    float r[8];
    #pragma unroll
    for (int j = 0; j < 8; ++j) r[j] = __fmul_rn(a[j], a[j]);
    #pragma unroll
    for (int i = 8; i < 128; i += 8)
        #pragma unroll
        for (int j = 0; j < 8; ++j)
            r[j] = __fadd_rn(r[j], __fmul_rn(a[i + j], a[i + j]));
    return __fadd_rn(__fadd_rn(__fadd_rn(r[0], r[1]), __fadd_rn(r[2], r[3])),
                     __fadd_rn(__fadd_rn(r[4], r[5]), __fadd_rn(r[6], r[7])));
}
__device__ __forceinline__ float pw256_sq(const float* __restrict__ a) {
    return __fadd_rn(pw128_sq(a), pw128_sq(a + 128));
}

__global__ void ne2_kernel(const float* __restrict__ cb, float* __restrict__ ne2) {
    int k = blockIdx.x * blockDim.x + threadIdx.x;
    if (k < NUM_EMB) ne2[k] = pw256_sq(cb + (size_t)k * DIM);
}
__global__ void nx2_kernel(const float* __restrict__ x, float* __restrict__ nx2) {
    int i = blockIdx.x * blockDim.x + threadIdx.x;
    if (i < N_INPUTS) nx2[i] = pw256_sq(x + (size_t)i * DIM);
}

// ---- f32 -> bf16 (RNE) conversion, 4 elems/thread ----
__global__ void cvt_bf16(const float* __restrict__ in, unsigned short* __restrict__ o, int n4) {
    int i = blockIdx.x * blockDim.x + threadIdx.x;
    if (i < n4) {
        float4 v = ((const float4*)in)[i];
        ushort4 u;
        u.x = f2bf_rne(v.x); u.y = f2bf_rne(v.y);
        u.z = f2bf_rne(v.z); u.w = f2bf_rne(v.w);
        ((ushort4*)o)[i] = u;
    }
}

// ---- exact score, bit-identical to round-2 kernel (passed indices exactly) ----
__device__ float exact_score(const float* __restrict__ xr, const float* __restrict__ er,
                             float nx2r, float ne2v) {
    float a = 0.f;
    for (int d = 0; d < DIM; d += 16) {
        float4 xa = *(const float4*)(xr + d);
        float4 xb = *(const float4*)(xr + d + 4);
        float4 xc = *(const float4*)(xr + d + 8);
        float4 xd = *(const float4*)(xr + d + 12);
        float4 e0 = *(const float4*)(er + d);
        float4 e1 = *(const float4*)(er + d + 4);
        float4 e2 = *(const float4*)(er + d + 8);
        float4 e3 = *(const float4*)(er + d + 12);
        a = fmaf(xa.x, e0.x, a); a = fmaf(xa.y, e0.y, a);
        a = fmaf(xa.z, e0.z, a); a = fmaf(xa.w, e0.w, a);
        a = fmaf(xb.x, e1.x, a); a = fmaf(xb.y, e1.y, a);
        a = fmaf(xb.z, e1.z, a); a = fmaf(xb.w, e1.w, a);
        a = fmaf(xc.x, e2.x, a); a = fmaf(xc.y, e2.y, a);
        a = fmaf(xc.z, e2.z, a); a = fmaf(xc.w, e2.w, a);
        a = fmaf(xd.x, e3.x, a); a = fmaf(xd.y, e3.y, a);
        a = fmaf(xd.z, e3.z, a); a = fmaf(xd.w, e3.w, a);
    }
    float t1 = __fadd_rn(nx2r, ne2v);
    return __fsub_rn(t1, __fmul_rn(2.f, a));
}

// ---- pass 1: MFMA GEMM + running-global-min + candidate append ----
__global__ __launch_bounds__(256) void gemm_cand(
        const unsigned short* __restrict__ xbf,   // [65536][256]
        const unsigned short* __restrict__ cbbf,  // [4096][256]
        const float* __restrict__ ne2,
        unsigned* __restrict__ cand_cnt,          // [65536]
        unsigned* __restrict__ cand_ent,          // [65536][CAP]
        unsigned long long* __restrict__ ma) {
    __shared__ __align__(16) short As[2][128 * 64];
    __shared__ __align__(16) short Bs[2][128 * 64];
    __shared__ unsigned long long smin[128][2];

    const int bid = blockIdx.x;
    const int remap = (bid & 7) * 2048 + (bid >> 3);   // XCD-chunked, bijective
    const int by = remap >> 5;                         // row tile 0..511
    const int bx = remap & 31;                         // col tile 0..31
    const size_t brow = (size_t)by * 128;
    const int bcol = bx * 128;

    const int tid = threadIdx.x;
    const int w = tid >> 6, lane = tid & 63;
    const int wr = w >> 1, wc = w & 1;

    f32x4 acc[4][4];
    #pragma unroll
    for (int m = 0; m < 4; ++m)
        #pragma unroll
        for (int n = 0; n < 4; ++n) acc[m][n] = (f32x4){0.f, 0.f, 0.f, 0.f};

    auto stage = [&](int buf, int t) {
        #pragma unroll
        for (int i = 0; i < 4; ++i) {
            int chunk = w * 4 + i;                 // 0..15, wave-uniform
            int row = chunk * 8 + (lane >> 3);
            const unsigned short* ga = xbf + (brow + row) * DIM + t * 64 + (lane & 7) * 8;
            const unsigned short* gb = cbbf + (size_t)(bcol + row) * DIM + t * 64 + (lane & 7) * 8;
            __builtin_amdgcn_global_load_lds(
                (const __attribute__((address_space(1))) unsigned*)ga,
                (__attribute__((address_space(3))) unsigned*)((char*)&As[buf][0] + chunk * 1024),
                16, 0, 0);
            __builtin_amdgcn_global_load_lds(
                (const __attribute__((address_space(1))) unsigned*)gb,
                (__attribute__((address_space(3))) unsigned*)((char*)&Bs[buf][0] + chunk * 1024),
                16, 0, 0);
        }
    };

    stage(0, 0);
    __syncthreads();
    #pragma unroll
    for (int t = 0; t < 4; ++t) {
        if (t < 3) stage((t + 1) & 1, t + 1);
        const int buf = t & 1;
        #pragma unroll
        for (int kk = 0; kk < 2; ++kk) {
            bf16x8 af[4], bg[4];
            #pragma unroll
            for (int m = 0; m < 4; ++m) {
                int rowl = wr * 64 + m * 16 + (lane & 15);
                af[m] = *(const bf16x8*)&As[buf][rowl * 64 + kk * 32 + (lane >> 4) * 8];
            }
            #pragma unroll
            for (int n = 0; n < 4; ++n) {
                int coll = wc * 64 + n * 16 + (lane & 15);
                bg[n] = *(const bf16x8*)&Bs[buf][coll * 64 + kk * 32 + (lane >> 4) * 8];
            }
            #pragma unroll
            for (int m = 0; m < 4; ++m)
                #pragma unroll
                for (int n = 0; n < 4; ++n)
                    acc[m][n] = __builtin_amdgcn_mfma_f32_16x16x32_bf16(af[m], bg[n], acc[m][n], 0, 0, 0);
        }
        __syncthreads();
    }

    // ---- epilogue: per-row tile min ----
    float ne2v[4];
    #pragma unroll
    for (int n = 0; n < 4; ++n) ne2v[n] = ne2[bcol + wc * 64 + n * 16 + (lane & 15)];

    #pragma unroll
    for (int m = 0; m < 4; ++m) {
        #pragma unroll
        for (int j = 0; j < 4; ++j) {
            unsigned long long best = ~0ull;
            #pragma unroll
            for (int n = 0; n < 4; ++n) {
                float s = __fsub_rn(ne2v[n], __fmul_rn(2.f, acc[m][n][j]));
                int col = bcol + wc * 64 + n * 16 + (lane & 15);
                unsigned long long p = ((unsigned long long)enc32(s) << 32) | (unsigned)col;
                best = best < p ? best : p;
            }
            #pragma unroll
            for (int off = 1; off < 16; off <<= 1) {
                unsigned long long o = __shfl_xor(best, off, 64);
                best = best < o ? best : o;
            }
            if ((lane & 15) == 0)
                smin[wr * 64 + m * 16 + (lane >> 4) * 4 + j][wc] = best;
        }
    }
    __syncthreads();

    // ---- fold in running global min (atomicMin returns previous value) ----
    if (tid < 128) {
        unsigned long long a = smin[tid][0], b = smin[tid][1];
        unsigned long long v = a < b ? a : b;
        unsigned long long prev = atomicMin(&ma[brow + tid], v);
        smin[tid][0] = prev < v ? prev : v;   // freshest known global min
    }
    __syncthreads();

    // ---- candidate append vs (global-ish min + TAU) ----
    #pragma unroll
    for (int m = 0; m < 4; ++m) {
        #pragma unroll
        for (int j = 0; j < 4; ++j) {
            int rowl = wr * 64 + m * 16 + (lane >> 4) * 4 + j;
            float thr = dec32((unsigned)(smin[rowl][0] >> 32)) + TAU;
            size_t rowg = brow + rowl;
            #pragma unroll
            for (int n = 0; n < 4; ++n) {
                float s = __fsub_rn(ne2v[n], __fmul_rn(2.f, acc[m][n][j]));
                if (s <= thr) {
                    int col = bcol + wc * 64 + n * 16 + (lane & 15);
                    int q = (int)rintf(s * QSCALE);
                    q = max(-32767, min(32767, q));
                    unsigned entry = ((unsigned)(q + 32768) << 16) | (unsigned)col;
                    unsigned pos = atomicAdd(&cand_cnt[rowg], 1u);
                    if (pos < CAP) cand_ent[rowg * CAP + pos] = entry;
                }
            }
        }
    }
}

// ---- pass 2: exact refine (one wave per row, loops ALL candidates) ----
__global__ __launch_bounds__(256) void refine_kernel(
        const float* __restrict__ x, const float* __restrict__ cb,
        const float* __restrict__ ne2, const float* __restrict__ nx2,
        const unsigned* __restrict__ cand_cnt, const unsigned* __restrict__ cand_ent,
        const unsigned long long* __restrict__ ma,
        float* __restrict__ out_idx, int* __restrict__ counts) {
    const size_t row = (size_t)blockIdx.x * 4 + (threadIdx.x >> 6);
    const int lane = threadIdx.x & 63;
    const unsigned cnt = cand_cnt[row];
    const float nx2r = nx2[row];
    const float* xr = x + row * DIM;
    unsigned long long best = ~0ull;

    if (cnt <= CAP) {
        float mav = dec32((unsigned)(ma[row] >> 32));
        int qthr = (int)rintf((mav + TAU) * QSCALE) + 1 + 32768;
        for (unsigned p = lane; p < cnt; p += 64) {
            unsigned e = cand_ent[row * CAP + p];
            int code = e & 0xFFFF;
            if ((int)(e >> 16) <= qthr) {
                float s = exact_score(xr, cb + (size_t)code * DIM, nx2r, ne2[code]);
                unsigned long long pk = ((unsigned long long)enc32(s) << 32) | (unsigned)code;
                best = best < pk ? best : pk;
            }
        }
    }
    #pragma unroll
    for (int off = 1; off < 64; off <<= 1) {
        unsigned long long o = __shfl_xor(best, off, 64);
        best = best < o ? best : o;
    }
    if (best == ~0ull) {  // overflow or empty candidate set: exact full scan
        unsigned long long b2 = ~0ull;
        for (int c = lane; c < NUM_EMB; c += 64) {
            float s = exact_score(xr, cb + (size_t)c * DIM, nx2r, ne2[c]);
            unsigned long long pk = ((unsigned long long)enc32(s) << 32) | (unsigned)c;
            b2 = b2 < pk ? b2 : pk;
        }
        #pragma unroll
        for (int off = 1; off < 64; off <<= 1) {
            unsigned long long o = __shfl_xor(b2, off, 64);
            b2 = b2 < o ? b2 : o;
        }
        best = b2;
    }
    if (lane == 0) {
        int idx = (int)(best & 0xFFFFFFFFull);
        idx = max(0, min(NUM_EMB - 1, idx));   // defensive: never OOB
        out_idx[row] = (float)idx;
        atomicAdd(&counts[idx], 1);
    }
}

// ---- pass 3: gather quantized + loss partials ----
__global__ __launch_bounds__(256) void outputs_kernel(
        const float* __restrict__ x, const float* __restrict__ cb,
        const float* __restrict__ out_idx, float* __restrict__ out_q,
        float* __restrict__ partials) {
    __shared__ float red[256];
    const int t = threadIdx.x, b = blockIdx.x;
    const size_t rowbase = (size_t)b * 64;
    const int r = t >> 2, c0 = (t & 3) * 16;
    const size_t row = rowbase + r;
    int qi = (int)out_idx[row];
    qi = max(0, min(NUM_EMB - 1, qi));         // defensive
    const float4* crq = (const float4*)(cb + (size_t)qi * DIM);
    const float4* xr4 = (const float4*)(x + row * DIM);
    float4* oq = (float4*)(out_q + row * DIM);
    float ss = 0.f;
    #pragma unroll
    for (int k = 0; k < 16; ++k) {
        float4 q = crq[c0 + k];
        float4 xv = xr4[c0 + k];
        oq[c0 + k] = q;
        float dx = xv.x - q.x, dy = xv.y - q.y, dz = xv.z - q.z, dw = xv.w - q.w;
        ss += dx * dx + dy * dy + dz * dz + dw * dw;
    }
    red[t] = ss; __syncthreads();
    for (int st = 128; st; st >>= 1) {
        if (t < st) red[t] += red[t + st];
        __syncthreads();
    }
    if (t == 0) partials[b] = red[0];
}

__global__ void finalize_kernel(const float* __restrict__ partials, int np,
                                const int* __restrict__ counts,
                                float* __restrict__ out_loss,
                                float* __restrict__ out_perp) {
    __shared__ double sh[256];
    const int t = threadIdx.x;
    double s = 0.0;
    for (int i = t; i < np; i += 256) s += (double)partials[i];
    sh[t] = s; __syncthreads();
    for (int st = 128; st; st >>= 1) { if (t < st) sh[t] += sh[t + st]; __syncthreads(); }
    double sse = sh[0];
    __syncthreads();
    double h = 0.0;
    for (int k = t; k < NUM_EMB; k += 256) {
        double p = (double)counts[k] / (double)N_INPUTS;
        h -= p * log(p + 1e-10);
    }
    sh[t] = h; __syncthreads();
    for (int st = 128; st; st >>= 1) { if (t < st) sh[t] += sh[t + st]; __syncthreads(); }
    if (t == 0) {
        double mse = sse / ((double)N_INPUTS * (double)DIM);
        out_loss[0] = (float)(1.25 * mse);
        out_perp[0] = (float)exp(sh[0]);
    }
}

extern "C" void kernel_launch(void* const* d_in, const int* in_sizes, int n_in,
                              void* d_out, int out_size, void* d_ws, size_t ws_size,
                              hipStream_t stream) {
    const float* x  = (const float*)d_in[0];
    const float* cb = (const float*)d_in[1];
    float* out      = (float*)d_out;

    float* out_q    = out;                           // 16777216 f32 (64 MiB)
    float* out_loss = out + (size_t)N_INPUTS * DIM;
    float* out_perp = out_loss + 1;
    float* out_idx  = out_perp + 1;                  // 65536 f32

    // scratch inside out_q region (fully rewritten by outputs_kernel at the end)
    char* sc = (char*)out_q;
    unsigned short* xbf    = (unsigned short*)(sc);                 // 32 MB
    unsigned short* cbbf   = (unsigned short*)(sc + 33554432);      // 2 MB
    unsigned long long* ma = (unsigned long long*)(sc + 35651584);  // 512 KB
    unsigned* cand_cnt     = (unsigned*)(sc + 36175872);            // 256 KB
    unsigned* cand_ent     = (unsigned*)(sc + 36438016);            // 23.7 MB, ends < 61.4 MB

    // ws (<= 300 KB, proven available in round 2)
    float* ne2      = (float*)d_ws;                       // 16 KB
    int*   counts   = (int*)((char*)d_ws + 16384);        // 16 KB
    float* partials = (float*)((char*)d_ws + 32768);      // 4 KB
    float* nx2      = (float*)((char*)d_ws + 36864);      // 256 KB

    hipMemsetAsync(counts, 0, NUM_EMB * sizeof(int), stream);
    hipMemsetAsync(cand_cnt, 0, (size_t)N_INPUTS * 4, stream);
    hipMemsetAsync(ma, 0xFF, (size_t)N_INPUTS * 8, stream);

    ne2_kernel<<<NUM_EMB / 256, 256, 0, stream>>>(cb, ne2);
    nx2_kernel<<<N_INPUTS / 256, 256, 0, stream>>>(x, nx2);
    cvt_bf16<<<(NUM_EMB * DIM / 4) / 256, 256, 0, stream>>>(cb, cbbf, NUM_EMB * DIM / 4);
    cvt_bf16<<<(N_INPUTS * DIM / 4) / 256, 256, 0, stream>>>(x, xbf, N_INPUTS * DIM / 4);

    gemm_cand<<<16384, 256, 0, stream>>>(xbf, cbbf, ne2, cand_cnt, cand_ent, ma);
    refine_kernel<<<N_INPUTS / 4, 256, 0, stream>>>(x, cb, ne2, nx2, cand_cnt, cand_ent,
                                                    ma, out_idx, counts);
    outputs_kernel<<<N_INPUTS / 64, 256, 0, stream>>>(x, cb, out_idx, out_q, partials);
    finalize_kernel<<<1, 256, 0, stream>>>(partials, N_INPUTS / 64, counts,
                                           out_loss, out_perp);
}

// Round 5
// 874.682 us; speedup vs baseline: 6.3730x; 1.1278x over previous
//
#include <hip/hip_runtime.h>
#include <hip/hip_bf16.h>
#include <math.h>

#define N_INPUTS 65536
#define NUM_EMB 4096
#define DIM 256
#define TAU_H 9.0e-4f     // half-score threshold (== 1.8e-3 full-scale, proven r4)
#define CAP 192

typedef __attribute__((ext_vector_type(8))) short bf16x8;
typedef __attribute__((ext_vector_type(4))) float f32x4;

// ---- monotone float<->uint packing ----
__device__ __forceinline__ unsigned enc32(float f) {
    unsigned u = __float_as_uint(f);
    return (u & 0x80000000u) ? ~u : (u | 0x80000000u);
}
__device__ __forceinline__ float dec32(unsigned e) {
    unsigned u = (e & 0x80000000u) ? (e & 0x7FFFFFFFu) : ~e;
    return __uint_as_float(u);
}
__device__ __forceinline__ unsigned short f2bf_rne(float f) {
    unsigned u = __float_as_uint(f);
    return (unsigned short)((u + 0x7FFFu + ((u >> 16) & 1u)) >> 16);
}

// ---- numpy pairwise sum of squares (bit-exact, proven r2) ----
__device__ __forceinline__ float pw128_sq(const float* __restrict__ a) {
    float r[8];
    #pragma unroll
    for (int j = 0; j < 8; ++j) r[j] = __fmul_rn(a[j], a[j]);
    #pragma unroll
    for (int i = 8; i < 128; i += 8)
        #pragma unroll
        for (int j = 0; j < 8; ++j)
            r[j] = __fadd_rn(r[j], __fmul_rn(a[i + j], a[i + j]));
    return __fadd_rn(__fadd_rn(__fadd_rn(r[0], r[1]), __fadd_rn(r[2], r[3])),
                     __fadd_rn(__fadd_rn(r[4], r[5]), __fadd_rn(r[6], r[7])));
}
__device__ __forceinline__ float pw256_sq(const float* __restrict__ a) {
    return __fadd_rn(pw128_sq(a), pw128_sq(a + 128));
}

// ---- prep: stage 64 rows in LDS -> row norms (numpy order) + bf16 copy ----
__global__ __launch_bounds__(256) void prep_rows(
        const float* __restrict__ src, float* __restrict__ norms,
        unsigned short* __restrict__ dst_bf) {
    __shared__ float xs[64 * 260];
    const int t = threadIdx.x, b = blockIdx.x;
    const size_t rowbase = (size_t)b * 64;
    const float4* g = (const float4*)(src + rowbase * DIM);
    float4* s4 = (float4*)xs;
    #pragma unroll
    for (int k = 0; k < 16; ++k) {
        int p = t + k * 256, r = p >> 6, c = p & 63;
        s4[r * 65 + c] = g[p];
    }
    __syncthreads();
    if (t < 64) norms[rowbase + t] = pw256_sq(xs + t * 260);
    #pragma unroll
    for (int k = 0; k < 16; ++k) {
        int p = t + k * 256, r = p >> 6, c = p & 63;
        float4 v = s4[r * 65 + c];
        ushort4 u;
        u.x = f2bf_rne(v.x); u.y = f2bf_rne(v.y);
        u.z = f2bf_rne(v.z); u.w = f2bf_rne(v.w);
        ((ushort4*)dst_bf)[(size_t)b * 4096 + p] = u;
    }
}

// ---- exact score, bit-identical to r2/r4 (passed indices exactly) ----
__device__ float exact_score(const float* __restrict__ xr, const float* __restrict__ er,
                             float nx2r, float ne2v) {
    float a = 0.f;
    for (int d = 0; d < DIM; d += 16) {
        float4 xa = *(const float4*)(xr + d);
        float4 xb = *(const float4*)(xr + d + 4);
        float4 xc = *(const float4*)(xr + d + 8);
        float4 xd = *(const float4*)(xr + d + 12);
        float4 e0 = *(const float4*)(er + d);
        float4 e1 = *(const float4*)(er + d + 4);
        float4 e2 = *(const float4*)(er + d + 8);
        float4 e3 = *(const float4*)(er + d + 12);
        a = fmaf(xa.x, e0.x, a); a = fmaf(xa.y, e0.y, a);
        a = fmaf(xa.z, e0.z, a); a = fmaf(xa.w, e0.w, a);
        a = fmaf(xb.x, e1.x, a); a = fmaf(xb.y, e1.y, a);
        a = fmaf(xb.z, e1.z, a); a = fmaf(xb.w, e1.w, a);
        a = fmaf(xc.x, e2.x, a); a = fmaf(xc.y, e2.y, a);
        a = fmaf(xc.z, e2.z, a); a = fmaf(xc.w, e2.w, a);
        a = fmaf(xd.x, e3.x, a); a = fmaf(xd.y, e3.y, a);
        a = fmaf(xd.z, e3.z, a); a = fmaf(xd.w, e3.w, a);
    }
    float t1 = __fadd_rn(nx2r, ne2v);
    return __fsub_rn(t1, __fmul_rn(2.f, a));
}

// ---- pass 1: MFMA GEMM + f32 min + candidate append ----
__global__ __launch_bounds__(256) void gemm_cand(
        const unsigned short* __restrict__ xbf,
        const unsigned short* __restrict__ cbbf,
        const float* __restrict__ ne2,
        unsigned* __restrict__ cand_cnt,
        unsigned short* __restrict__ cand_ent,
        unsigned* __restrict__ ma) {
    __shared__ __align__(16) short As[2][128 * 64];
    __shared__ __align__(16) short Bs[2][128 * 64];
    __shared__ float smin[128][2];

    const int bid = blockIdx.x;
    const int by = bid & 511;          // row panel (inner: one batch = all rows)
    const int bx = bid >> 9;           // col tile (outer: batches serialize)
    const size_t brow = (size_t)by * 128;
    const int bcol = bx * 128;

    const int tid = threadIdx.x;
    const int w = tid >> 6, lane = tid & 63;
    const int wr = w >> 1, wc = w & 1;

    f32x4 acc[4][4];
    #pragma unroll
    for (int m = 0; m < 4; ++m)
        #pragma unroll
        for (int n = 0; n < 4; ++n) acc[m][n] = (f32x4){0.f, 0.f, 0.f, 0.f};

    // pre-swizzled global source: LDS(row, c) holds global (row, c ^ ((row&7)<<4))
    auto stage = [&](int buf, int tt) {
        const int srcoff = (int)(((lane & 7) << 4) ^ ((lane >> 3) << 4));
        #pragma unroll
        for (int i = 0; i < 4; ++i) {
            int chunk = w * 4 + i;                  // wave-uniform
            int row = chunk * 8 + (lane >> 3);      // row&7 == lane>>3
            const char* ga = (const char*)xbf + (brow + row) * 512 + tt * 128 + srcoff;
            const char* gb = (const char*)cbbf + (size_t)(bcol + row) * 512 + tt * 128 + srcoff;
            __builtin_amdgcn_global_load_lds(
                (const __attribute__((address_space(1))) unsigned*)ga,
                (__attribute__((address_space(3))) unsigned*)((char*)&As[buf][0] + chunk * 1024),
                16, 0, 0);
            __builtin_amdgcn_global_load_lds(
                (const __attribute__((address_space(1))) unsigned*)gb,
                (__attribute__((address_space(3))) unsigned*)((char*)&Bs[buf][0] + chunk * 1024),
                16, 0, 0);
        }
    };

    stage(0, 0);
    __syncthreads();
    #pragma unroll
    for (int tt = 0; tt < 4; ++tt) {
        if (tt < 3) stage((tt + 1) & 1, tt + 1);
        const int buf = tt & 1;
        const int xorb = (lane & 7) << 4;           // read-side un-swizzle
        #pragma unroll
        for (int kk = 0; kk < 2; ++kk) {
            const int kb = kk * 64 + (lane >> 4) * 16;
            const int cswz = kb ^ xorb;
            bf16x8 af[4], bg[4];
            #pragma unroll
            for (int m = 0; m < 4; ++m) {
                int rowl = wr * 64 + m * 16 + (lane & 15);   // rowl&7 == lane&7
                af[m] = *(const bf16x8*)((const char*)&As[buf][0] + rowl * 128 + cswz);
            }
            #pragma unroll
            for (int n = 0; n < 4; ++n) {
                int coll = wc * 64 + n * 16 + (lane & 15);
                bg[n] = *(const bf16x8*)((const char*)&Bs[buf][0] + coll * 128 + cswz);
            }
            #pragma unroll
            for (int m = 0; m < 4; ++m)
                #pragma unroll
                for (int n = 0; n < 4; ++n)
                    acc[m][n] = __builtin_amdgcn_mfma_f32_16x16x32_bf16(af[m], bg[n], acc[m][n], 0, 0, 0);
        }
        __syncthreads();
    }

    // ---- epilogue: half-scores s' = 0.5*ne2 - dot; f32-only min ----
    float ne2h[4];
    #pragma unroll
    for (int n = 0; n < 4; ++n)
        ne2h[n] = 0.5f * ne2[bcol + wc * 64 + n * 16 + (lane & 15)];

    #pragma unroll
    for (int m = 0; m < 4; ++m) {
        #pragma unroll
        for (int j = 0; j < 4; ++j) {
            float v = fminf(fminf(ne2h[0] - acc[m][0][j], ne2h[1] - acc[m][1][j]),
                            fminf(ne2h[2] - acc[m][2][j], ne2h[3] - acc[m][3][j]));
            #pragma unroll
            for (int off = 1; off < 16; off <<= 1)
                v = fminf(v, __shfl_xor(v, off, 64));
            if ((lane & 15) == 0)
                smin[wr * 64 + m * 16 + (lane >> 4) * 4 + j][wc] = v;
        }
    }
    __syncthreads();

    if (tid < 128) {
        float v = fminf(smin[tid][0], smin[tid][1]);
        unsigned mu = ma[brow + tid];                  // relaxed read (stale ok)
        float cur = (mu == 0xFFFFFFFFu) ? INFINITY : dec32(mu);
        atomicMin(&ma[brow + tid], enc32(v));          // fire-and-forget
        smin[tid][0] = fminf(v, cur) + TAU_H;          // append threshold
    }
    __syncthreads();

    #pragma unroll
    for (int m = 0; m < 4; ++m) {
        #pragma unroll
        for (int j = 0; j < 4; ++j) {
            int rowl = wr * 64 + m * 16 + (lane >> 4) * 4 + j;
            float thr = smin[rowl][0];
            size_t rowg = brow + rowl;
            #pragma unroll
            for (int n = 0; n < 4; ++n) {
                float s = ne2h[n] - acc[m][n][j];
                if (s <= thr) {
                    int col = bcol + wc * 64 + n * 16 + (lane & 15);
                    unsigned pos = atomicAdd(&cand_cnt[rowg], 1u);
                    if (pos < CAP) cand_ent[rowg * CAP + pos] = (unsigned short)col;
                }
            }
        }
    }
}

// ---- pass 2: exact refine (one wave per row) ----
__global__ __launch_bounds__(256) void refine_kernel(
        const float* __restrict__ x, const float* __restrict__ cb,
        const float* __restrict__ ne2, const float* __restrict__ nx2,
        const unsigned* __restrict__ cand_cnt,
        const unsigned short* __restrict__ cand_ent,
        float* __restrict__ out_idx, int* __restrict__ counts) {
    const size_t row = (size_t)blockIdx.x * 4 + (threadIdx.x >> 6);
    const int lane = threadIdx.x & 63;
    const unsigned cnt = cand_cnt[row];
    const float nx2r = nx2[row];
    const float* xr = x + row * DIM;
    unsigned long long best = ~0ull;

    if (cnt <= CAP) {
        for (unsigned p = lane; p < cnt; p += 64) {
            int code = cand_ent[row * CAP + p];
            float s = exact_score(xr, cb + (size_t)code * DIM, nx2r, ne2[code]);
            unsigned long long pk = ((unsigned long long)enc32(s) << 32) | (unsigned)code;
            best = best < pk ? best : pk;
        }
    }
    #pragma unroll
    for (int off = 1; off < 64; off <<= 1) {
        unsigned long long o = __shfl_xor(best, off, 64);
        best = best < o ? best : o;
    }
    if (best == ~0ull) {   // overflow: exact full scan (always correct)
        unsigned long long b2 = ~0ull;
        for (int c = lane; c < NUM_EMB; c += 64) {
            float s = exact_score(xr, cb + (size_t)c * DIM, nx2r, ne2[c]);
            unsigned long long pk = ((unsigned long long)enc32(s) << 32) | (unsigned)c;
            b2 = b2 < pk ? b2 : pk;
        }
        #pragma unroll
        for (int off = 1; off < 64; off <<= 1) {
            unsigned long long o = __shfl_xor(b2, off, 64);
            b2 = b2 < o ? b2 : o;
        }
        best = b2;
    }
    if (lane == 0) {
        int idx = (int)(best & 0xFFFFFFFFull);
        idx = max(0, min(NUM_EMB - 1, idx));
        out_idx[row] = (float)idx;
        atomicAdd(&counts[idx], 1);
    }
}

// ---- pass 3: gather quantized + loss partials ----
__global__ __launch_bounds__(256) void outputs_kernel(
        const float* __restrict__ x, const float* __restrict__ cb,
        const float* __restrict__ out_idx, float* __restrict__ out_q,
        float* __restrict__ partials) {
    __shared__ float red[256];
    const int t = threadIdx.x, b = blockIdx.x;
    const size_t rowbase = (size_t)b * 64;
    const int r = t >> 2, c0 = (t & 3) * 16;
    const size_t row = rowbase + r;
    int qi = (int)out_idx[row];
    qi = max(0, min(NUM_EMB - 1, qi));
    const float4* crq = (const float4*)(cb + (size_t)qi * DIM);
    const float4* xr4 = (const float4*)(x + row * DIM);
    float4* oq = (float4*)(out_q + row * DIM);
    float ss = 0.f;
    #pragma unroll
    for (int k = 0; k < 16; ++k) {
        float4 q = crq[c0 + k];
        float4 xv = xr4[c0 + k];
        oq[c0 + k] = q;
        float dx = xv.x - q.x, dy = xv.y - q.y, dz = xv.z - q.z, dw = xv.w - q.w;
        ss += dx * dx + dy * dy + dz * dz + dw * dw;
    }
    red[t] = ss; __syncthreads();
    for (int st = 128; st; st >>= 1) {
        if (t < st) red[t] += red[t + st];
        __syncthreads();
    }
    if (t == 0) partials[b] = red[0];
}

__global__ void finalize_kernel(const float* __restrict__ partials, int np,
                                const int* __restrict__ counts,
                                float* __restrict__ out_loss,
                                float* __restrict__ out_perp) {
    __shared__ double sh[256];
    const int t = threadIdx.x;
    double s = 0.0;
    for (int i = t; i < np; i += 256) s += (double)partials[i];
    sh[t] = s; __syncthreads();
    for (int st = 128; st; st >>= 1) { if (t < st) sh[t] += sh[t + st]; __syncthreads(); }
    double sse = sh[0];
    __syncthreads();
    double h = 0.0;
    for (int k = t; k < NUM_EMB; k += 256) {
        double p = (double)counts[k] / (double)N_INPUTS;
        h -= p * log(p + 1e-10);
    }
    sh[t] = h; __syncthreads();
    for (int st = 128; st; st >>= 1) { if (t < st) sh[t] += sh[t + st]; __syncthreads(); }
    if (t == 0) {
        double mse = sse / ((double)N_INPUTS * (double)DIM);
        out_loss[0] = (float)(1.25 * mse);
        out_perp[0] = (float)exp(sh[0]);
    }
}

extern "C" void kernel_launch(void* const* d_in, const int* in_sizes, int n_in,
                              void* d_out, int out_size, void* d_ws, size_t ws_size,
                              hipStream_t stream) {
    const float* x  = (const float*)d_in[0];
    const float* cb = (const float*)d_in[1];
    float* out      = (float*)d_out;

    float* out_q    = out;                           // 16777216 f32 (64 MiB)
    float* out_loss = out + (size_t)N_INPUTS * DIM;
    float* out_perp = out_loss + 1;
    float* out_idx  = out_perp + 1;

    // scratch inside out_q region (rewritten by outputs_kernel at the end)
    char* sc = (char*)out_q;
    unsigned short* xbf     = (unsigned short*)(sc);                 // 32 MB
    unsigned short* cbbf    = (unsigned short*)(sc + 33554432);      // 2 MB
    unsigned* ma            = (unsigned*)(sc + 35651584);            // 256 KB
    unsigned* cand_cnt      = (unsigned*)(sc + 35913728);            // 256 KB
    unsigned short* cand_ent = (unsigned short*)(sc + 36175872);     // 24 MB, ends 61.3 MB

    float* ne2      = (float*)d_ws;                       // 16 KB
    int*   counts   = (int*)((char*)d_ws + 16384);        // 16 KB
    float* partials = (float*)((char*)d_ws + 32768);      // 4 KB
    float* nx2      = (float*)((char*)d_ws + 36864);      // 256 KB

    hipMemsetAsync(counts, 0, NUM_EMB * sizeof(int), stream);
    hipMemsetAsync(cand_cnt, 0, (size_t)N_INPUTS * 4, stream);
    hipMemsetAsync(ma, 0xFF, (size_t)N_INPUTS * 4, stream);

    prep_rows<<<N_INPUTS / 64, 256, 0, stream>>>(x, nx2, xbf);
    prep_rows<<<NUM_EMB / 64, 256, 0, stream>>>(cb, ne2, cbbf);

    gemm_cand<<<16384, 256, 0, stream>>>(xbf, cbbf, ne2, cand_cnt, cand_ent, ma);
    refine_kernel<<<N_INPUTS / 4, 256, 0, stream>>>(x, cb, ne2, nx2, cand_cnt, cand_ent,
                                                    out_idx, counts);
    outputs_kernel<<<N_INPUTS / 64, 256, 0, stream>>>(x, cb, out_idx, out_q, partials);
    finalize_kernel<<<1, 256, 0, stream>>>(partials, N_INPUTS / 64, counts,
                                           out_loss, out_perp);
}